// Round 2
// baseline (710.165 us; speedup 1.0000x reference)
//
#include <hip/hip_runtime.h>
#include <stdint.h>

// DPMultiheadAttention, MI355X bf16-MFMA implementation.
// L=2048, N=4, E=1024, H=16, D=64.
// Q is pre-scaled by D^-0.5 * log2(e) so softmax uses exp2 directly.
// k_avg recomputes QK^T from the same Qa/Ka bits as k_attn -> identical
// scores -> rows of avg sum to exactly 1/denominator consistency.

typedef __attribute__((ext_vector_type(8))) short bf16x8;
typedef __attribute__((ext_vector_type(4))) float f32x4;

#define MFMA(a, b, c) __builtin_amdgcn_mfma_f32_16x16x32_bf16((a), (b), (c), 0, 0, 0)

__device__ __forceinline__ ushort f2bf(float f) {
    uint32_t u = __builtin_bit_cast(uint32_t, f);
    u += 0x7fffu + ((u >> 16) & 1u);   // round-to-nearest-even
    return (ushort)(u >> 16);
}

// ---------------------------------------------------------------------------
// K1: QKV projections. z=0: Q (scaled), z=1: K, z=2: V (output transposed by
// swapping A/B roles so that Vt[bh][d][s] has coalesced GEMM semantics).
// out[r][e] = X[r][:] . W[e][:] + b[e]   (r = l*4+n, e = h*64+d)
// ---------------------------------------------------------------------------
__global__ __launch_bounds__(256) void k_proj(
    const float* __restrict__ Xq, const float* __restrict__ Xk, const float* __restrict__ Xv,
    const float* __restrict__ Wq, const float* __restrict__ bq,
    const float* __restrict__ Wk, const float* __restrict__ bk,
    const float* __restrict__ Wv, const float* __restrict__ bv,
    ushort* __restrict__ Qa, ushort* __restrict__ Ka, ushort* __restrict__ Vt)
{
    const int z = blockIdx.z;
    const float* X = (z == 0) ? Xq : (z == 1) ? Xk : Xv;
    const float* W = (z == 0) ? Wq : (z == 1) ? Wk : Wv;
    const float* B = (z == 0) ? bq : (z == 1) ? bk : bv;

    __shared__ __align__(16) ushort xt[128][40];   // X tile [row][k], +8 pad
    __shared__ __align__(16) ushort wt[128][40];   // W tile [row][k]

    const int t = threadIdx.x;
    const int lane = t & 63;
    const int w = t >> 6;             // wave 0..3
    const int wr = w >> 1, wc = w & 1;
    const int c = lane & 15, g = lane >> 4;

    const int xrow0 = blockIdx.x * 128;   // X rows (r)
    const int wrow0 = blockIdx.y * 128;   // W rows (e)

    f32x4 acc[4][4] = {};

    for (int kt = 0; kt < 32; ++kt) {
        const int k0 = kt * 32;
        __syncthreads();
#pragma unroll
        for (int i = 0; i < 4; ++i) {
            int slot = t + i * 256;
            int row = slot >> 3, seg = slot & 7;
            float4 xv4 = *(const float4*)(X + (size_t)(xrow0 + row) * 1024 + k0 + seg * 4);
            uint2 px;
            px.x = (uint)f2bf(xv4.x) | ((uint)f2bf(xv4.y) << 16);
            px.y = (uint)f2bf(xv4.z) | ((uint)f2bf(xv4.w) << 16);
            *(uint2*)&xt[row][seg * 4] = px;
            float4 wv4 = *(const float4*)(W + (size_t)(wrow0 + row) * 1024 + k0 + seg * 4);
            uint2 pw;
            pw.x = (uint)f2bf(wv4.x) | ((uint)f2bf(wv4.y) << 16);
            pw.y = (uint)f2bf(wv4.z) | ((uint)f2bf(wv4.w) << 16);
            *(uint2*)&wt[row][seg * 4] = pw;
        }
        __syncthreads();

        const ushort (*At)[40] = (z == 2) ? wt : xt;   // A rows = output rows
        const ushort (*Bt)[40] = (z == 2) ? xt : wt;   // B rows = output cols
        bf16x8 af[4], bfr[4];
#pragma unroll
        for (int m = 0; m < 4; ++m) af[m]  = *(const bf16x8*)&At[wr * 64 + m * 16 + c][g * 8];
#pragma unroll
        for (int n = 0; n < 4; ++n) bfr[n] = *(const bf16x8*)&Bt[wc * 64 + n * 16 + c][g * 8];
#pragma unroll
        for (int m = 0; m < 4; ++m)
#pragma unroll
            for (int n = 0; n < 4; ++n)
                acc[m][n] = MFMA(af[m], bfr[n], acc[m][n]);
    }

    const float QS = 0.125f * 1.44269504088896340736f;  // D^-0.5 * log2(e)
#pragma unroll
    for (int m = 0; m < 4; ++m)
#pragma unroll
        for (int n = 0; n < 4; ++n)
#pragma unroll
            for (int i = 0; i < 4; ++i) {
                int rowi = ((z == 2) ? wrow0 : xrow0) + wr * 64 + m * 16 + 4 * g + i;
                int coli = ((z == 2) ? xrow0 : wrow0) + wc * 64 + n * 16 + c;
                int e = (z == 2) ? rowi : coli;
                int r = (z == 2) ? coli : rowi;
                float v = acc[m][n][i] + B[e];
                if (z == 0) v *= QS;
                ushort bv16 = f2bf(v);
                int nn = r & 3, l = r >> 2, h = e >> 6, d = e & 63;
                int bh = nn * 16 + h;
                if (z == 2) Vt[((size_t)bh * 64 + d) * 2048 + l] = bv16;
                else {
                    ushort* o = (z == 0) ? Qa : Ka;
                    o[((size_t)bh * 2048 + l) * 64 + d] = bv16;
                }
            }
}

// ---------------------------------------------------------------------------
// K2: flash attention per (q-tile of 128 rows, bh). 8 waves x 16 rows each,
// per-wave online softmax over full S. Saves running max m and denom l.
// ---------------------------------------------------------------------------
__global__ __launch_bounds__(512) void k_attn(
    const ushort* __restrict__ Qa, const ushort* __restrict__ Ka, const ushort* __restrict__ Vt,
    ushort* __restrict__ ctx, float* __restrict__ mbuf, float* __restrict__ lbuf)
{
    __shared__ __align__(16) ushort kt[64][72];       // K tile [s][d], +8 pad
    __shared__ __align__(16) ushort vt[64][72];       // V tile [d][s], +8 pad
    __shared__ __align__(16) ushort pt[8][16][72];    // per-wave P tile [l][s]

    const int t = threadIdx.x;
    const int lane = t & 63;
    const int w = t >> 6;             // 0..7
    const int c = lane & 15, g = lane >> 4;
    const int bh = blockIdx.y;
    const int n = bh >> 4, h = bh & 15;
    const int l0 = blockIdx.x * 128;
    const int lrow = l0 + w * 16 + c;

    bf16x8 aq0 = *(const bf16x8*)(Qa + ((size_t)bh * 2048 + lrow) * 64 + g * 8);
    bf16x8 aq1 = *(const bf16x8*)(Qa + ((size_t)bh * 2048 + lrow) * 64 + 32 + g * 8);

    f32x4 O[4] = {};
    float mrow[4] = {-1e30f, -1e30f, -1e30f, -1e30f};
    float lpart[4] = {0.f, 0.f, 0.f, 0.f};

    for (int st = 0; st < 32; ++st) {
        __syncthreads();
        {
            int row = t >> 3, seg = t & 7;
            *(uint4*)&kt[row][seg * 8] =
                *(const uint4*)(Ka + ((size_t)bh * 2048 + st * 64 + row) * 64 + seg * 8);
            *(uint4*)&vt[row][seg * 8] =
                *(const uint4*)(Vt + ((size_t)bh * 64 + row) * 2048 + st * 64 + seg * 8);
        }
        __syncthreads();

        // QK^T: scores 16 x 64 per wave
        f32x4 s[4];
#pragma unroll
        for (int ct = 0; ct < 4; ++ct) {
            bf16x8 b0 = *(const bf16x8*)&kt[ct * 16 + c][g * 8];
            bf16x8 b1 = *(const bf16x8*)&kt[ct * 16 + c][32 + g * 8];
            f32x4 zf = {};
            zf = MFMA(aq0, b0, zf);
            s[ct] = MFMA(aq1, b1, zf);
        }

        float tm[4];
#pragma unroll
        for (int i = 0; i < 4; ++i)
            tm[i] = fmaxf(fmaxf(s[0][i], s[1][i]), fmaxf(s[2][i], s[3][i]));
#pragma unroll
        for (int i = 0; i < 4; ++i) {
            tm[i] = fmaxf(tm[i], __shfl_xor(tm[i], 1));
            tm[i] = fmaxf(tm[i], __shfl_xor(tm[i], 2));
            tm[i] = fmaxf(tm[i], __shfl_xor(tm[i], 4));
            tm[i] = fmaxf(tm[i], __shfl_xor(tm[i], 8));
        }
#pragma unroll
        for (int i = 0; i < 4; ++i) {
            float mn = fmaxf(mrow[i], tm[i]);
            float al = exp2f(mrow[i] - mn);
            mrow[i] = mn;
            lpart[i] *= al;
            O[0][i] *= al; O[1][i] *= al; O[2][i] *= al; O[3][i] *= al;
        }
#pragma unroll
        for (int ct = 0; ct < 4; ++ct)
#pragma unroll
            for (int i = 0; i < 4; ++i) {
                float p = exp2f(s[ct][i] - mrow[i]);
                lpart[i] += p;
                pt[w][4 * g + i][ct * 16 + c] = f2bf(p);
            }

        // PV (per-wave P tile: same-wave LDS ordering, no barrier needed)
        bf16x8 ap0 = *(const bf16x8*)&pt[w][c][g * 8];
        bf16x8 ap1 = *(const bf16x8*)&pt[w][c][32 + g * 8];
#pragma unroll
        for (int dt = 0; dt < 4; ++dt) {
            bf16x8 b0 = *(const bf16x8*)&vt[dt * 16 + c][g * 8];
            bf16x8 b1 = *(const bf16x8*)&vt[dt * 16 + c][32 + g * 8];
            O[dt] = MFMA(ap0, b0, O[dt]);
            O[dt] = MFMA(ap1, b1, O[dt]);
        }
    }

    float lr[4];
#pragma unroll
    for (int i = 0; i < 4; ++i) {
        float v = lpart[i];
        v += __shfl_xor(v, 1); v += __shfl_xor(v, 2);
        v += __shfl_xor(v, 4); v += __shfl_xor(v, 8);
        lr[i] = v;
    }
#pragma unroll
    for (int i = 0; i < 4; ++i) {
        float rl = 1.0f / lr[i];
        int l = l0 + w * 16 + 4 * g + i;
        size_t base = ((size_t)l * 4 + n) * 1024 + h * 64;
#pragma unroll
        for (int dt = 0; dt < 4; ++dt)
            ctx[base + dt * 16 + c] = f2bf(O[dt][i] * rl);
    }
    if (c == 0) {
#pragma unroll
        for (int i = 0; i < 4; ++i) {
            int l = l0 + w * 16 + 4 * g + i;
            mbuf[(size_t)bh * 2048 + l] = mrow[i];
            lbuf[(size_t)bh * 2048 + l] = lr[i];
        }
    }
}

// ---------------------------------------------------------------------------
// K3: output projection  out = ctx @ Wo^T + bo  (f32 out, coalesced)
// ---------------------------------------------------------------------------
__global__ __launch_bounds__(256) void k_oproj(
    const ushort* __restrict__ ctx, const float* __restrict__ Wo,
    const float* __restrict__ bo, float* __restrict__ out)
{
    __shared__ __align__(16) ushort xt[128][40];
    __shared__ __align__(16) ushort wt[128][40];

    const int t = threadIdx.x;
    const int lane = t & 63;
    const int w = t >> 6;
    const int wr = w >> 1, wc = w & 1;
    const int c = lane & 15, g = lane >> 4;

    const int r0 = blockIdx.x * 128;
    const int e0 = blockIdx.y * 128;

    f32x4 acc[4][4] = {};

    for (int kt = 0; kt < 32; ++kt) {
        const int k0 = kt * 32;
        __syncthreads();
#pragma unroll
        for (int i = 0; i < 2; ++i) {     // ctx tile: bf16 straight copy
            int slot = t + i * 256;
            int row = slot >> 2, seg = slot & 3;
            *(uint4*)&xt[row][seg * 8] =
                *(const uint4*)(ctx + (size_t)(r0 + row) * 1024 + k0 + seg * 8);
        }
#pragma unroll
        for (int i = 0; i < 4; ++i) {     // Wo tile: f32 -> bf16
            int slot = t + i * 256;
            int row = slot >> 3, seg = slot & 7;
            float4 wv4 = *(const float4*)(Wo + (size_t)(e0 + row) * 1024 + k0 + seg * 4);
            uint2 pw;
            pw.x = (uint)f2bf(wv4.x) | ((uint)f2bf(wv4.y) << 16);
            pw.y = (uint)f2bf(wv4.z) | ((uint)f2bf(wv4.w) << 16);
            *(uint2*)&wt[row][seg * 4] = pw;
        }
        __syncthreads();

        bf16x8 af[4], bfr[4];
#pragma unroll
        for (int m = 0; m < 4; ++m) af[m]  = *(const bf16x8*)&xt[wr * 64 + m * 16 + c][g * 8];
#pragma unroll
        for (int n = 0; n < 4; ++n) bfr[n] = *(const bf16x8*)&wt[wc * 64 + n * 16 + c][g * 8];
#pragma unroll
        for (int m = 0; m < 4; ++m)
#pragma unroll
            for (int n = 0; n < 4; ++n)
                acc[m][n] = MFMA(af[m], bfr[n], acc[m][n]);
    }

#pragma unroll
    for (int m = 0; m < 4; ++m)
#pragma unroll
        for (int n = 0; n < 4; ++n)
#pragma unroll
            for (int i = 0; i < 4; ++i) {
                int r = r0 + wr * 64 + m * 16 + 4 * g + i;
                int e = e0 + wc * 64 + n * 16 + c;
                out[(size_t)r * 1024 + e] = acc[m][n][i] + bo[e];
            }
}

// ---------------------------------------------------------------------------
// K4: head-averaged attention weights. Recompute QK^T with saved (m, l),
// register-accumulate sum over heads, single coalesced write (no atomics).
// ---------------------------------------------------------------------------
__global__ __launch_bounds__(512) void k_avg(
    const ushort* __restrict__ Qa, const ushort* __restrict__ Ka,
    const float* __restrict__ mbuf, const float* __restrict__ lbuf,
    float* __restrict__ avg)
{
    __shared__ float ms[16][64];
    __shared__ float rs[16][64];

    const int t = threadIdx.x;
    const int lane = t & 63;
    const int w = t >> 6;
    const int wr = w >> 2, wc = w & 3;
    const int c = lane & 15, g = lane >> 4;
    const int n = blockIdx.z;
    const int l0 = blockIdx.y * 64;
    const int s0 = blockIdx.x * 512 + wc * 128;

    for (int idx = t; idx < 1024; idx += 512) {
        int hh = idx >> 6, row = idx & 63;
        ms[hh][row] = mbuf[(size_t)(n * 16 + hh) * 2048 + l0 + row];
        rs[hh][row] = 1.0f / (16.0f * lbuf[(size_t)(n * 16 + hh) * 2048 + l0 + row]);
    }
    __syncthreads();

    f32x4 acc[2][8] = {};

    for (int h = 0; h < 16; ++h) {
        const int bh = n * 16 + h;
        bf16x8 aq[2][2];
#pragma unroll
        for (int rt = 0; rt < 2; ++rt) {
            int row = l0 + wr * 32 + rt * 16 + c;
            aq[rt][0] = *(const bf16x8*)(Qa + ((size_t)bh * 2048 + row) * 64 + g * 8);
            aq[rt][1] = *(const bf16x8*)(Qa + ((size_t)bh * 2048 + row) * 64 + 32 + g * 8);
        }
        float mr[8], rl[8];
#pragma unroll
        for (int rt = 0; rt < 2; ++rt)
#pragma unroll
            for (int i = 0; i < 4; ++i) {
                mr[rt * 4 + i] = ms[h][wr * 32 + rt * 16 + 4 * g + i];
                rl[rt * 4 + i] = rs[h][wr * 32 + rt * 16 + 4 * g + i];
            }
#pragma unroll
        for (int ct = 0; ct < 8; ++ct) {
            int srow = s0 + ct * 16 + c;
            bf16x8 b0 = *(const bf16x8*)(Ka + ((size_t)bh * 2048 + srow) * 64 + g * 8);
            bf16x8 b1 = *(const bf16x8*)(Ka + ((size_t)bh * 2048 + srow) * 64 + 32 + g * 8);
#pragma unroll
            for (int rt = 0; rt < 2; ++rt) {
                f32x4 zf = {};
                zf = MFMA(aq[rt][0], b0, zf);
                zf = MFMA(aq[rt][1], b1, zf);
#pragma unroll
                for (int i = 0; i < 4; ++i)
                    acc[rt][ct][i] += exp2f(zf[i] - mr[rt * 4 + i]) * rl[rt * 4 + i];
            }
        }
    }

#pragma unroll
    for (int rt = 0; rt < 2; ++rt)
#pragma unroll
        for (int i = 0; i < 4; ++i) {
            int row = l0 + wr * 32 + rt * 16 + 4 * g + i;
#pragma unroll
            for (int ct = 0; ct < 8; ++ct)
                avg[((size_t)n * 2048 + row) * 2048 + s0 + ct * 16 + c] = acc[rt][ct][i];
        }
}

// ---------------------------------------------------------------------------
extern "C" void kernel_launch(void* const* d_in, const int* in_sizes, int n_in,
                              void* d_out, int out_size, void* d_ws, size_t ws_size,
                              hipStream_t stream)
{
    const float* query = (const float*)d_in[0];
    const float* key   = (const float*)d_in[1];
    const float* value = (const float*)d_in[2];
    const float* Wq = (const float*)d_in[3];
    const float* bq = (const float*)d_in[4];
    const float* Wk = (const float*)d_in[5];
    const float* bk = (const float*)d_in[6];
    const float* Wv = (const float*)d_in[7];
    const float* bv = (const float*)d_in[8];
    const float* Wo = (const float*)d_in[9];
    const float* bo = (const float*)d_in[10];

    float* out = (float*)d_out;                 // attn_output: 8,388,608 f32
    float* avg = out + 8388608;                 // avg_weights: 16,777,216 f32

    // Workspace (33.5 MB): Qa, Ka bf16 [64][2048][64]; m/l stats.
    ushort* Qa = (ushort*)d_ws;                 // 8,388,608 bf16
    ushort* Ka = Qa + 8388608;                  // 8,388,608 bf16
    float* mbuf = (float*)(Ka + 8388608);       // 131,072 f32
    float* lbuf = mbuf + 131072;                // 131,072 f32

    // Vt and ctx parked inside d_out's avg region (written later by k_avg):
    //   Vt  = avg floats [0 .. 4,194,304)    (16 MB as bf16 [64][64][2048])
    //   ctx = avg floats [12,582,912 .. end) (16 MB as bf16 [8192][1024])
    // Launch order k_attn -> k_oproj -> k_avg keeps this safe on every call.
    ushort* Vt  = (ushort*)avg;
    ushort* ctx = (ushort*)(out + 20971520);

    k_proj<<<dim3(64, 8, 3), 256, 0, stream>>>(query, key, value,
                                               Wq, bq, Wk, bk, Wv, bv,
                                               Qa, Ka, Vt);
    k_attn<<<dim3(16, 64), 512, 0, stream>>>(Qa, Ka, Vt, ctx, mbuf, lbuf);
    k_oproj<<<dim3(64, 8), 256, 0, stream>>>(ctx, Wo, bo, out);
    k_avg<<<dim3(4, 32, 4), 512, 0, stream>>>(Qa, Ka, mbuf, lbuf, avg);
}

// Round 4
// 620.928 us; speedup vs baseline: 1.1437x; 1.1437x over previous
//
#include <hip/hip_runtime.h>
#include <stdint.h>

// DPMultiheadAttention, MI355X bf16-MFMA implementation. Round 3 (resubmit).
// L=2048, N=4, E=1024, H=16, D=64.
// Q pre-scaled by D^-0.5*log2(e); softmax in exp2 domain.
// k_attn: swapped QK^T (mfma(K,Q)) -> lane-local softmax (q = lane&15),
//         PV computed as O^T = mfma(V^T, P) -> lane-local rescale,
//         post-loop LDS transpose for coalesced ctx writes.
// k_prep: one-pass f32->bf16 conversion of X,W so GEMM staging is pure copies.

typedef __attribute__((ext_vector_type(8))) short bf16x8;
typedef __attribute__((ext_vector_type(4))) short s16x4;
typedef __attribute__((ext_vector_type(4))) float f32x4;

#define MFMA(a, b, c) __builtin_amdgcn_mfma_f32_16x16x32_bf16((a), (b), (c), 0, 0, 0)

__device__ __forceinline__ ushort f2bf(float f) {
    uint32_t u = __builtin_bit_cast(uint32_t, f);
    u += 0x7fffu + ((u >> 16) & 1u);   // round-to-nearest-even
    return (ushort)(u >> 16);
}

// ---------------------------------------------------------------------------
// K0: f32 -> bf16 pre-conversion (X: z=0..2, W: z=3..6). Memory-bound.
// ---------------------------------------------------------------------------
__global__ __launch_bounds__(256) void k_prep(
    const float* __restrict__ xq, const float* __restrict__ xk, const float* __restrict__ xv,
    const float* __restrict__ wq, const float* __restrict__ wk,
    const float* __restrict__ wv, const float* __restrict__ wo,
    ushort* __restrict__ xqb, ushort* __restrict__ xkb, ushort* __restrict__ xvb,
    ushort* __restrict__ wqb, ushort* __restrict__ wkb,
    ushort* __restrict__ wvb, ushort* __restrict__ wob)
{
    const int z = blockIdx.y;
    const float* src; ushort* dst; int n8;
    switch (z) {
        case 0: src = xq; dst = xqb; n8 = 1048576; break;
        case 1: src = xk; dst = xkb; n8 = 1048576; break;
        case 2: src = xv; dst = xvb; n8 = 1048576; break;
        case 3: src = wq; dst = wqb; n8 = 131072;  break;
        case 4: src = wk; dst = wkb; n8 = 131072;  break;
        case 5: src = wv; dst = wvb; n8 = 131072;  break;
        default: src = wo; dst = wob; n8 = 131072; break;
    }
    int u = blockIdx.x * 256 + threadIdx.x;
    if (u >= n8) return;
    const float4* s4 = (const float4*)src;
    float4 a = s4[2 * (size_t)u];
    float4 b = s4[2 * (size_t)u + 1];
    uint4 o;
    o.x = (uint)f2bf(a.x) | ((uint)f2bf(a.y) << 16);
    o.y = (uint)f2bf(a.z) | ((uint)f2bf(a.w) << 16);
    o.z = (uint)f2bf(b.x) | ((uint)f2bf(b.y) << 16);
    o.w = (uint)f2bf(b.z) | ((uint)f2bf(b.w) << 16);
    *(uint4*)(dst + 8 * (size_t)u) = o;
}

// ---------------------------------------------------------------------------
// K1: QKV projections from bf16 inputs. z=0: Q (scaled), z=1: K, z=2: V
// (V transposed by swapping A/B roles -> Vt[bh][d][s]).
// ---------------------------------------------------------------------------
__global__ __launch_bounds__(256) void k_proj(
    const ushort* __restrict__ Xq, const ushort* __restrict__ Xk, const ushort* __restrict__ Xv,
    const ushort* __restrict__ Wqb, const ushort* __restrict__ Wkb, const ushort* __restrict__ Wvb,
    const float* __restrict__ bq, const float* __restrict__ bk, const float* __restrict__ bv,
    ushort* __restrict__ Qa, ushort* __restrict__ Ka, ushort* __restrict__ Vt)
{
    const int z = blockIdx.z;
    const ushort* X = (z == 0) ? Xq : (z == 1) ? Xk : Xv;
    const ushort* W = (z == 0) ? Wqb : (z == 1) ? Wkb : Wvb;
    const float* B = (z == 0) ? bq : (z == 1) ? bk : bv;

    __shared__ __align__(16) ushort xt[128][40];   // +8 pad
    __shared__ __align__(16) ushort wt[128][40];

    const int t = threadIdx.x;
    const int lane = t & 63;
    const int w = t >> 6;
    const int wr = w >> 1, wc = w & 1;
    const int c = lane & 15, g = lane >> 4;

    const int xrow0 = blockIdx.x * 128;
    const int wrow0 = blockIdx.y * 128;

    f32x4 acc[4][4] = {};

    for (int kt = 0; kt < 32; ++kt) {
        const int k0 = kt * 32;
        __syncthreads();
#pragma unroll
        for (int i = 0; i < 2; ++i) {
            int slot = t + i * 256;
            int row = slot >> 2, seg = slot & 3;
            *(uint4*)&xt[row][seg * 8] =
                *(const uint4*)(X + (size_t)(xrow0 + row) * 1024 + k0 + seg * 8);
            *(uint4*)&wt[row][seg * 8] =
                *(const uint4*)(W + (size_t)(wrow0 + row) * 1024 + k0 + seg * 8);
        }
        __syncthreads();

        const ushort (*At)[40] = (z == 2) ? wt : xt;
        const ushort (*Bt)[40] = (z == 2) ? xt : wt;
        bf16x8 af[4], bfr[4];
#pragma unroll
        for (int m = 0; m < 4; ++m) af[m]  = *(const bf16x8*)&At[wr * 64 + m * 16 + c][g * 8];
#pragma unroll
        for (int n = 0; n < 4; ++n) bfr[n] = *(const bf16x8*)&Bt[wc * 64 + n * 16 + c][g * 8];
#pragma unroll
        for (int m = 0; m < 4; ++m)
#pragma unroll
            for (int n = 0; n < 4; ++n)
                acc[m][n] = MFMA(af[m], bfr[n], acc[m][n]);
    }

    const float QS = 0.125f * 1.44269504088896340736f;
#pragma unroll
    for (int m = 0; m < 4; ++m)
#pragma unroll
        for (int n = 0; n < 4; ++n)
#pragma unroll
            for (int i = 0; i < 4; ++i) {
                int rowi = ((z == 2) ? wrow0 : xrow0) + wr * 64 + m * 16 + 4 * g + i;
                int coli = ((z == 2) ? xrow0 : wrow0) + wc * 64 + n * 16 + c;
                int e = (z == 2) ? rowi : coli;
                int r = (z == 2) ? coli : rowi;
                float v = acc[m][n][i] + B[e];
                if (z == 0) v *= QS;
                ushort bv16 = f2bf(v);
                int nn = r & 3, l = r >> 2, h = e >> 6, d = e & 63;
                int bh = nn * 16 + h;
                if (z == 2) Vt[((size_t)bh * 64 + d) * 2048 + l] = bv16;
                else {
                    ushort* o = (z == 0) ? Qa : Ka;
                    o[((size_t)bh * 2048 + l) * 64 + d] = bv16;
                }
            }
}

// ---------------------------------------------------------------------------
// K2: flash attention, swapped-operand form. Per wave: 16 q rows (q=lane&15),
// KV tile 64. Scores S^T = mfma(K,Q): lane holds S[kv=ct*16+4g+r][q=c].
// Softmax fully lane-local (+2 shfl_xor for cross-group max/sum).
// PV as O^T = mfma(V^T, P): lane holds O[q=c][d=dt*16+4g+r] -> local rescale.
// ---------------------------------------------------------------------------
__global__ __launch_bounds__(512) void k_attn(
    const ushort* __restrict__ Qa, const ushort* __restrict__ Ka, const ushort* __restrict__ Vt,
    ushort* __restrict__ ctx, float* __restrict__ mbuf, float* __restrict__ lbuf)
{
    // smem: kt[64][72] | vt[64][72] | pt: 8 waves x [16][72]
    __shared__ __align__(16) ushort smem[4608 * 2 + 8 * 16 * 72];
    ushort (*kt)[72] = (ushort(*)[72])smem;
    ushort (*vt)[72] = (ushort(*)[72])(smem + 4608);

    const int t = threadIdx.x;
    const int lane = t & 63;
    const int w = t >> 6;
    const int c = lane & 15, g = lane >> 4;
    ushort* ptw = smem + 9216 + w * 1152;          // wave-private [16][72]
    const int bh = blockIdx.y;
    const int n = bh >> 4, h = bh & 15;
    const int l0 = blockIdx.x * 128;
    const int lrow = l0 + w * 16 + c;              // this lane's q row

    // Q B-fragment: lane needs Q[q=c][k=g*8+e]
    bf16x8 aq0 = *(const bf16x8*)(Qa + ((size_t)bh * 2048 + lrow) * 64 + g * 8);
    bf16x8 aq1 = *(const bf16x8*)(Qa + ((size_t)bh * 2048 + lrow) * 64 + 32 + g * 8);

    f32x4 O[4] = {};             // O[dt][r] = O[q=c][d=dt*16+4g+r]
    float m = -1e30f, l = 0.f;   // per-lane online softmax state for q=c

    for (int st = 0; st < 32; ++st) {
        __syncthreads();
        {
            int row = t >> 3, seg = t & 7;
            *(uint4*)&kt[row][seg * 8] =
                *(const uint4*)(Ka + ((size_t)bh * 2048 + st * 64 + row) * 64 + seg * 8);
            *(uint4*)&vt[row][seg * 8] =
                *(const uint4*)(Vt + ((size_t)bh * 64 + row) * 2048 + st * 64 + seg * 8);
        }
        __syncthreads();

        // S^T = mfma(A=K, B=Q): sc[ct][r] = S[kv=ct*16+4g+r][q=c]
        f32x4 sc[4];
#pragma unroll
        for (int ct = 0; ct < 4; ++ct) {
            bf16x8 kb0 = *(const bf16x8*)&kt[ct * 16 + c][g * 8];
            bf16x8 kb1 = *(const bf16x8*)&kt[ct * 16 + c][32 + g * 8];
            f32x4 z = {};
            z = MFMA(kb0, aq0, z);
            sc[ct] = MFMA(kb1, aq1, z);
        }

        // row max: local 16 + cross-group (xor16 merges g-pairs, xor32 halves)
        float pm = fmaxf(fmaxf(sc[0][0], sc[0][1]), fmaxf(sc[0][2], sc[0][3]));
#pragma unroll
        for (int ct = 1; ct < 4; ++ct)
            pm = fmaxf(pm, fmaxf(fmaxf(sc[ct][0], sc[ct][1]), fmaxf(sc[ct][2], sc[ct][3])));
        pm = fmaxf(pm, __shfl_xor(pm, 16));
        pm = fmaxf(pm, __shfl_xor(pm, 32));

        float mn = fmaxf(m, pm);
        float al = exp2f(m - mn);
        m = mn;
        l *= al;
        O[0] *= al; O[1] *= al; O[2] *= al; O[3] *= al;   // lane-local rescale

        // P = exp2(S - m), pack to bf16 pairs, wave-private LDS (b64 writes)
#pragma unroll
        for (int ct = 0; ct < 4; ++ct) {
            float p0 = exp2f(sc[ct][0] - m);
            float p1 = exp2f(sc[ct][1] - m);
            float p2 = exp2f(sc[ct][2] - m);
            float p3 = exp2f(sc[ct][3] - m);
            l += (p0 + p1) + (p2 + p3);
            uint pa, pb;
            asm("v_cvt_pk_bf16_f32 %0, %1, %2" : "=v"(pa) : "v"(p0), "v"(p1));
            asm("v_cvt_pk_bf16_f32 %0, %1, %2" : "=v"(pb) : "v"(p2), "v"(p3));
            uint64_t pk = (uint64_t)pa | ((uint64_t)pb << 32);
            *(s16x4*)&ptw[c * 72 + ct * 16 + g * 4] = __builtin_bit_cast(s16x4, pk);
        }

        // O^T = mfma(A=V^T, B=P): A[d][kv]=vt[d][kv], B[q][kv]=ptw[q][kv]
        bf16x8 ap0 = *(const bf16x8*)&ptw[c * 72 + g * 8];
        bf16x8 ap1 = *(const bf16x8*)&ptw[c * 72 + 32 + g * 8];
#pragma unroll
        for (int dt = 0; dt < 4; ++dt) {
            bf16x8 vb0 = *(const bf16x8*)&vt[dt * 16 + c][g * 8];
            bf16x8 vb1 = *(const bf16x8*)&vt[dt * 16 + c][32 + g * 8];
            O[dt] = MFMA(vb0, ap0, O[dt]);
            O[dt] = MFMA(vb1, ap1, O[dt]);
        }
    }

    // final denom for q=c
    float lsum = l;
    lsum += __shfl_xor(lsum, 16);
    lsum += __shfl_xor(lsum, 32);
    float rl = 1.0f / lsum;

    // transpose O through LDS (pad 65 to spread banks), coalesced ctx write
    __syncthreads();
    float* otw = (float*)smem + w * 1040;          // wave-private [16][65]
#pragma unroll
    for (int dt = 0; dt < 4; ++dt)
#pragma unroll
        for (int r = 0; r < 4; ++r)
            otw[c * 65 + dt * 16 + 4 * g + r] = O[dt][r] * rl;
#pragma unroll
    for (int qq = 0; qq < 16; ++qq) {
        float v = otw[qq * 65 + lane];
        int lr2 = l0 + w * 16 + qq;
        ctx[((size_t)lr2 * 4 + n) * 1024 + h * 64 + lane] = f2bf(v);
    }
    if (g == 0) {
        mbuf[(size_t)bh * 2048 + l0 + w * 16 + c] = m;
        lbuf[(size_t)bh * 2048 + l0 + w * 16 + c] = lsum;
    }
}

// ---------------------------------------------------------------------------
// K3: output projection  out = ctx @ Wo^T + bo  (bf16 Wo pre-converted)
// ---------------------------------------------------------------------------
__global__ __launch_bounds__(256) void k_oproj(
    const ushort* __restrict__ ctx, const ushort* __restrict__ Wob,
    const float* __restrict__ bo, float* __restrict__ out)
{
    __shared__ __align__(16) ushort xt[128][40];
    __shared__ __align__(16) ushort wt[128][40];

    const int t = threadIdx.x;
    const int lane = t & 63;
    const int w = t >> 6;
    const int wr = w >> 1, wc = w & 1;
    const int c = lane & 15, g = lane >> 4;

    const int r0 = blockIdx.x * 128;
    const int e0 = blockIdx.y * 128;

    f32x4 acc[4][4] = {};

    for (int kt = 0; kt < 32; ++kt) {
        const int k0 = kt * 32;
        __syncthreads();
#pragma unroll
        for (int i = 0; i < 2; ++i) {
            int slot = t + i * 256;
            int row = slot >> 2, seg = slot & 3;
            *(uint4*)&xt[row][seg * 8] =
                *(const uint4*)(ctx + (size_t)(r0 + row) * 1024 + k0 + seg * 8);
            *(uint4*)&wt[row][seg * 8] =
                *(const uint4*)(Wob + (size_t)(e0 + row) * 1024 + k0 + seg * 8);
        }
        __syncthreads();

        bf16x8 af[4], bfr[4];
#pragma unroll
        for (int m = 0; m < 4; ++m) af[m]  = *(const bf16x8*)&xt[wr * 64 + m * 16 + c][g * 8];
#pragma unroll
        for (int n = 0; n < 4; ++n) bfr[n] = *(const bf16x8*)&wt[wc * 64 + n * 16 + c][g * 8];
#pragma unroll
        for (int m = 0; m < 4; ++m)
#pragma unroll
            for (int n = 0; n < 4; ++n)
                acc[m][n] = MFMA(af[m], bfr[n], acc[m][n]);
    }

#pragma unroll
    for (int m = 0; m < 4; ++m)
#pragma unroll
        for (int n = 0; n < 4; ++n)
#pragma unroll
            for (int i = 0; i < 4; ++i) {
                int r = r0 + wr * 64 + m * 16 + 4 * g + i;
                int e = e0 + wc * 64 + n * 16 + c;
                out[(size_t)r * 1024 + e] = acc[m][n][i] + bo[e];
            }
}

// ---------------------------------------------------------------------------
// K4: head-averaged attention weights (scores recomputed from the same Qa/Ka
// bits with saved m,l -> consistent with k_attn normalization).
// ---------------------------------------------------------------------------
__global__ __launch_bounds__(512) void k_avg(
    const ushort* __restrict__ Qa, const ushort* __restrict__ Ka,
    const float* __restrict__ mbuf, const float* __restrict__ lbuf,
    float* __restrict__ avg)
{
    __shared__ float ms[16][64];
    __shared__ float rs[16][64];

    const int t = threadIdx.x;
    const int lane = t & 63;
    const int w = t >> 6;
    const int wr = w >> 2, wc = w & 3;
    const int c = lane & 15, g = lane >> 4;
    const int n = blockIdx.z;
    const int l0 = blockIdx.y * 64;
    const int s0 = blockIdx.x * 512 + wc * 128;

    for (int idx = t; idx < 1024; idx += 512) {
        int hh = idx >> 6, row = idx & 63;
        ms[hh][row] = mbuf[(size_t)(n * 16 + hh) * 2048 + l0 + row];
        rs[hh][row] = 1.0f / (16.0f * lbuf[(size_t)(n * 16 + hh) * 2048 + l0 + row]);
    }
    __syncthreads();

    f32x4 acc[2][8] = {};

    for (int h = 0; h < 16; ++h) {
        const int bh = n * 16 + h;
        bf16x8 aq[2][2];
#pragma unroll
        for (int rt = 0; rt < 2; ++rt) {
            int row = l0 + wr * 32 + rt * 16 + c;
            aq[rt][0] = *(const bf16x8*)(Qa + ((size_t)bh * 2048 + row) * 64 + g * 8);
            aq[rt][1] = *(const bf16x8*)(Qa + ((size_t)bh * 2048 + row) * 64 + 32 + g * 8);
        }
        float mr[8], rl[8];
#pragma unroll
        for (int rt = 0; rt < 2; ++rt)
#pragma unroll
            for (int i = 0; i < 4; ++i) {
                mr[rt * 4 + i] = ms[h][wr * 32 + rt * 16 + 4 * g + i];
                rl[rt * 4 + i] = rs[h][wr * 32 + rt * 16 + 4 * g + i];
            }
#pragma unroll
        for (int ct = 0; ct < 8; ++ct) {
            int srow = s0 + ct * 16 + c;
            bf16x8 b0 = *(const bf16x8*)(Ka + ((size_t)bh * 2048 + srow) * 64 + g * 8);
            bf16x8 b1 = *(const bf16x8*)(Ka + ((size_t)bh * 2048 + srow) * 64 + 32 + g * 8);
#pragma unroll
            for (int rt = 0; rt < 2; ++rt) {
                f32x4 zf = {};
                zf = MFMA(aq[rt][0], b0, zf);
                zf = MFMA(aq[rt][1], b1, zf);
#pragma unroll
                for (int i = 0; i < 4; ++i)
                    acc[rt][ct][i] += exp2f(zf[i] - mr[rt * 4 + i]) * rl[rt * 4 + i];
            }
        }
    }

#pragma unroll
    for (int rt = 0; rt < 2; ++rt)
#pragma unroll
        for (int i = 0; i < 4; ++i) {
            int row = l0 + wr * 32 + rt * 16 + 4 * g + i;
#pragma unroll
            for (int ct = 0; ct < 8; ++ct)
                avg[((size_t)n * 2048 + row) * 2048 + s0 + ct * 16 + c] = acc[rt][ct][i];
        }
}

// ---------------------------------------------------------------------------
extern "C" void kernel_launch(void* const* d_in, const int* in_sizes, int n_in,
                              void* d_out, int out_size, void* d_ws, size_t ws_size,
                              hipStream_t stream)
{
    const float* query = (const float*)d_in[0];
    const float* key   = (const float*)d_in[1];
    const float* value = (const float*)d_in[2];
    const float* Wq = (const float*)d_in[3];
    const float* bq = (const float*)d_in[4];
    const float* Wk = (const float*)d_in[5];
    const float* bk = (const float*)d_in[6];
    const float* Wv = (const float*)d_in[7];
    const float* bv = (const float*)d_in[8];
    const float* Wo = (const float*)d_in[9];
    const float* bo = (const float*)d_in[10];

    float* out = (float*)d_out;                 // attn_output: 8,388,608 f32
    float* avg = out + 8388608;                 // avg_weights: 16,777,216 f32

    // Workspace (34.6 MB): Qa, Ka bf16; m/l stats.
    ushort* Qa = (ushort*)d_ws;                 // 8,388,608 bf16
    ushort* Ka = Qa + 8388608;                  // 8,388,608 bf16
    float* mbuf = (float*)(Ka + 8388608);       // 131,072 f32
    float* lbuf = mbuf + 131072;                // 131,072 f32

    // Scratch parked in d_out (lifetimes ordered by launch sequence):
    //   out region  (16,777,216 ushorts): Xbq | Xbk    (die before k_oproj)
    //   avg region  (33,554,432 ushorts):
    //     Vt  [0 .. 8,388,608)            (dies at k_avg)
    //     Xbv [8,388,608 .. 16,777,216)   (dies after k_proj)
    //     Wb  [16,777,216 .. 20,971,520)  (Wqb,Wkb,Wvb,Wob; die before k_avg)
    //     ctx [25,165,824 .. 33,554,432)  (dies at k_avg)
    ushort* ob  = (ushort*)out;
    ushort* av16 = (ushort*)avg;
    ushort* Xbq = ob;
    ushort* Xbk = ob + 8388608;
    ushort* Vt  = av16;
    ushort* Xbv = av16 + 8388608;
    ushort* Wqb = av16 + 16777216;
    ushort* Wkb = Wqb + 1048576;
    ushort* Wvb = Wkb + 1048576;
    ushort* Wob = Wvb + 1048576;
    ushort* ctx = av16 + 25165824;

    k_prep<<<dim3(4096, 7), 256, 0, stream>>>(query, key, value, Wq, Wk, Wv, Wo,
                                              Xbq, Xbk, Xbv, Wqb, Wkb, Wvb, Wob);
    k_proj<<<dim3(64, 8, 3), 256, 0, stream>>>(Xbq, Xbk, Xbv, Wqb, Wkb, Wvb,
                                               bq, bk, bv, Qa, Ka, Vt);
    k_attn<<<dim3(16, 64), 512, 0, stream>>>(Qa, Ka, Vt, ctx, mbuf, lbuf);
    k_oproj<<<dim3(64, 8), 256, 0, stream>>>(ctx, Wob, bo, out);
    k_avg<<<dim3(4, 32, 4), 512, 0, stream>>>(Qa, Ka, mbuf, lbuf, avg);
}